// Round 1
// baseline (3371.228 us; speedup 1.0000x reference)
//
#include <hip/hip_runtime.h>

#define T_OBS 512
#define HID   48
#define NB    4            // batch elements per wave
#define WAVES 4            // waves per block
#define BPB   (NB*WAVES)   // batch elements per block = 16

typedef float vf4 __attribute__((ext_vector_type(4)));

// sigmoid(x) = 1/(1+2^(-x*log2 e)) ; tanh(x) = 1 - 2/(1+2^(2x*log2 e))
__device__ __forceinline__ float sigm(float v) {
    return __builtin_amdgcn_rcpf(1.f + __builtin_amdgcn_exp2f(-1.44269504089f * v));
}
__device__ __forceinline__ float tanh_f(float v) {
    return 1.f - 2.f * __builtin_amdgcn_rcpf(1.f + __builtin_amdgcn_exp2f(2.88539008178f * v));
}

__global__ __launch_bounds__(256) void lstm2_kernel(
    const float* __restrict__ x,
    const float* __restrict__ Wih0, const float* __restrict__ Whh0,
    const float* __restrict__ bih0, const float* __restrict__ bhh0,
    const float* __restrict__ Wih1, const float* __restrict__ Whh1,
    const float* __restrict__ bih1, const float* __restrict__ bhh1,
    const float* __restrict__ Wlin, const float* __restrict__ blin,
    const int* __restrict__ fut,
    float* __restrict__ out)
{
    // Weights transposed to [k][j*4+q]: lane j reads its unit's 4 gates as one b128.
    __shared__ __attribute__((aligned(16))) float s_w0[48*192];   // W_hh0
    __shared__ __attribute__((aligned(16))) float s_w1[96*192];   // [W_ih1 ; W_hh1]
    __shared__ __attribute__((aligned(16))) float s_b0[192];
    __shared__ __attribute__((aligned(16))) float s_b1[192];
    __shared__ __attribute__((aligned(16))) float s_wi0[192];
    __shared__ __attribute__((aligned(16))) float s_wl[48];
    // per-wave h buffer, layout [row][batch]: rows 0..47 = h0, 48..95 = h1
    __shared__ __attribute__((aligned(16))) float s_hb[WAVES*96*4];

    const int tid = threadIdx.x;

    // ---- stage weights into LDS (once; cost amortized over 576 steps) ----
    for (int i = tid; i < 192*48; i += 256) {
        const int r = i / 48;            // row in [0,192): r = q*48 + j
        const int k = i - r*48;          // col in [0,48)
        const int dst = (r % 48)*4 + (r / 48);  // j*4 + q
        s_w0[k*192 + dst]      = Whh0[i];
        s_w1[k*192 + dst]      = Wih1[i];
        s_w1[(48+k)*192 + dst] = Whh1[i];
    }
    if (tid < 192) {
        const int j = tid >> 2, q = tid & 3;
        const int r = q*48 + j;
        s_b0[tid]  = bih0[r] + bhh0[r];
        s_b1[tid]  = bih1[r] + bhh1[r];
        s_wi0[tid] = Wih0[r];
        if (tid < 48) s_wl[tid] = Wlin[tid];
    }

    const int wave = tid >> 6, lane = tid & 63;
    const int jeff = (lane < 48) ? lane : 47;   // clamp idle lanes (harmless dup reads)
    const bool active = (lane < 48);
    float* hb = s_hb + wave*96*4;
    if (active) {
        *(vf4*)(hb + jeff*4)      = (vf4)0.f;
        *(vf4*)(hb + (48+jeff)*4) = (vf4)0.f;
    }
    __syncthreads();

    const int F    = fut[0];
    const int Ttot = T_OBS + F;
    const int bb0  = blockIdx.x * BPB + wave * NB;
    const float bl = blin[0];
    const vf4 b0v  = *(const vf4*)(s_b0  + jeff*4);
    const vf4 b1v  = *(const vf4*)(s_b1  + jeff*4);
    const vf4 wi0v = *(const vf4*)(s_wi0 + jeff*4);
    const float wl = s_wl[jeff];

    float c0[NB], c1[NB], cur[NB], oprev[NB];
    #pragma unroll
    for (int n = 0; n < NB; ++n) {
        c0[n] = 0.f; c1[n] = 0.f; oprev[n] = 0.f;
        cur[n] = x[(bb0 + n) * T_OBS];
    }

    for (int t = 0; t < Ttot; ++t) {
        // prefetch next x while computing this step
        float inp[NB], nxt[NB];
        const int tn = (t + 1 < T_OBS) ? (t + 1) : (T_OBS - 1);
        #pragma unroll
        for (int n = 0; n < NB; ++n) {
            nxt[n] = x[(bb0 + n) * T_OBS + tn];
            inp[n] = (t < T_OBS) ? cur[n] : oprev[n];
        }

        // ---------- layer 0: gates = b0 + Wih0*inp + Whh0 @ h0 ----------
        float acc[NB][4];
        #pragma unroll
        for (int n = 0; n < NB; ++n)
            #pragma unroll
            for (int q = 0; q < 4; ++q)
                acc[n][q] = b0v[q] + wi0v[q] * inp[n];

        #pragma unroll 4
        for (int k = 0; k < 48; ++k) {
            const vf4 w = *(const vf4*)(s_w0 + k*192 + jeff*4);
            const vf4 h = *(const vf4*)(hb + k*4);          // broadcast: h0[k] for 4 batches
            #pragma unroll
            for (int n = 0; n < NB; ++n)
                #pragma unroll
                for (int q = 0; q < 4; ++q)
                    acc[n][q] = fmaf(w[q], h[n], acc[n][q]);
        }

        float h0v[NB];
        #pragma unroll
        for (int n = 0; n < NB; ++n) {
            const float ig = sigm(acc[n][0]);
            const float fg = sigm(acc[n][1]);
            const float gg = tanh_f(acc[n][2]);
            const float og = sigm(acc[n][3]);
            c0[n]  = fg * c0[n] + ig * gg;
            h0v[n] = og * tanh_f(c0[n]);
        }
        if (active) {
            vf4 hv; hv[0]=h0v[0]; hv[1]=h0v[1]; hv[2]=h0v[2]; hv[3]=h0v[3];
            *(vf4*)(hb + jeff*4) = hv;                       // h0 rows for layer 1 + next step
        }

        // ---------- layer 1: gates = b1 + [Wih1;Whh1] @ [h0;h1] ----------
        #pragma unroll
        for (int n = 0; n < NB; ++n)
            #pragma unroll
            for (int q = 0; q < 4; ++q)
                acc[n][q] = b1v[q];

        #pragma unroll 4
        for (int k = 0; k < 96; ++k) {
            const vf4 w = *(const vf4*)(s_w1 + k*192 + jeff*4);
            const vf4 h = *(const vf4*)(hb + k*4);          // rows 0..47 h0(new), 48..95 h1(prev)
            #pragma unroll
            for (int n = 0; n < NB; ++n)
                #pragma unroll
                for (int q = 0; q < 4; ++q)
                    acc[n][q] = fmaf(w[q], h[n], acc[n][q]);
        }

        float h1v[NB];
        #pragma unroll
        for (int n = 0; n < NB; ++n) {
            const float ig = sigm(acc[n][0]);
            const float fg = sigm(acc[n][1]);
            const float gg = tanh_f(acc[n][2]);
            const float og = sigm(acc[n][3]);
            c1[n]  = fg * c1[n] + ig * gg;
            h1v[n] = og * tanh_f(c1[n]);
        }
        if (active) {
            vf4 hv; hv[0]=h1v[0]; hv[1]=h1v[1]; hv[2]=h1v[2]; hv[3]=h1v[3];
            *(vf4*)(hb + (48+jeff)*4) = hv;
        }

        // ---------- linear head: out = h1 . Wlin + b ----------
        float o[NB];
        #pragma unroll
        for (int n = 0; n < NB; ++n) {
            float s = active ? h1v[n] * wl : 0.f;
            #pragma unroll
            for (int d = 1; d < 64; d <<= 1)
                s += __shfl_xor(s, d, 64);                   // all lanes end with the sum
            o[n] = s + bl;
        }
        if (lane < NB) {
            float v = o[0];
            if (lane == 1) v = o[1];
            if (lane == 2) v = o[2];
            if (lane == 3) v = o[3];
            out[(bb0 + lane) * Ttot + t] = v;
        }
        #pragma unroll
        for (int n = 0; n < NB; ++n) { oprev[n] = o[n]; cur[n] = nxt[n]; }
    }
}

extern "C" void kernel_launch(void* const* d_in, const int* in_sizes, int n_in,
                              void* d_out, int out_size, void* d_ws, size_t ws_size,
                              hipStream_t stream) {
    const float* x    = (const float*)d_in[0];
    const float* Wih0 = (const float*)d_in[1];
    const float* Whh0 = (const float*)d_in[2];
    const float* bih0 = (const float*)d_in[3];
    const float* bhh0 = (const float*)d_in[4];
    const float* Wih1 = (const float*)d_in[5];
    const float* Whh1 = (const float*)d_in[6];
    const float* bih1 = (const float*)d_in[7];
    const float* bhh1 = (const float*)d_in[8];
    const float* Wlin = (const float*)d_in[9];
    const float* blin = (const float*)d_in[10];
    const int*   fut  = (const int*)d_in[11];
    float* out = (float*)d_out;

    const int B = in_sizes[0] / T_OBS;    // 4096
    const int grid = B / BPB;             // 256 blocks -> 1 per CU
    lstm2_kernel<<<grid, 256, 0, stream>>>(
        x, Wih0, Whh0, bih0, bhh0, Wih1, Whh1, bih1, bhh1, Wlin, blin, fut, out);
}